// Round 3
// baseline (351.838 us; speedup 1.0000x reference)
//
#include <hip/hip_runtime.h>
#include <hip/hip_bf16.h>

#define B_ 4
#define T_ 2048
#define D_ 1024
#define H_ 16
#define HD_ 64

typedef __bf16 bf16;
typedef __bf16 bf16x8 __attribute__((ext_vector_type(8)));
typedef __bf16 bf16x4 __attribute__((ext_vector_type(4)));
typedef float f32x4 __attribute__((ext_vector_type(4)));

#define MFMA16(a, b, c) __builtin_amdgcn_mfma_f32_16x16x32_bf16(a, b, c, 0, 0, 0)

__device__ inline void gld_lds16(const bf16* g, bf16* l) {
  __builtin_amdgcn_global_load_lds((const __attribute__((address_space(1))) void*)g,
                                   (__attribute__((address_space(3))) void*)l, 16, 0, 0);
}

// ---------------- convert x f32 -> bf16 ----------------
__global__ void cvt_f32_bf16(const float* __restrict__ in, bf16* __restrict__ out) {
  int i = (blockIdx.x * 256 + threadIdx.x) * 4;
  float4 v = *(const float4*)(in + i);
  bf16x4 o = {(bf16)v.x, (bf16)v.y, (bf16)v.z, (bf16)v.w};
  *(bf16x4*)(out + i) = o;
}

// ---------------- transpose f32 [R][C] -> bf16 [C][R] ----------------
__global__ void transpose_f32_bf16(const float* __restrict__ in, bf16* __restrict__ out,
                                   int R, int C) {
  __shared__ float tile[32][33];
  int c0 = blockIdx.x * 32, r0 = blockIdx.y * 32;
  int tx = threadIdx.x, ty = threadIdx.y;
#pragma unroll
  for (int i = 0; i < 4; i++)
    tile[ty + i * 8][tx] = in[(size_t)(r0 + ty + i * 8) * C + c0 + tx];
  __syncthreads();
#pragma unroll
  for (int i = 0; i < 4; i++)
    out[(size_t)(c0 + ty + i * 8) * R + r0 + tx] = (bf16)tile[tx][ty + i * 8];
}

// ---------------- transpose V bf16 [bh][T][64] -> [bh][64][T] ----------------
__global__ void transpose_v(const bf16* __restrict__ in, bf16* __restrict__ out) {
  __shared__ bf16 tile[32][33];
  int bh = blockIdx.y;
  int t0 = blockIdx.x * 32;
  int tx = threadIdx.x, ty = threadIdx.y;
  const bf16* ib = in + (size_t)bh * T_ * HD_;
  bf16* ob = out + (size_t)bh * HD_ * T_;
#pragma unroll
  for (int d0 = 0; d0 < 64; d0 += 32) {
#pragma unroll
    for (int i = 0; i < 4; i++)
      tile[ty + i * 8][tx] = ib[(size_t)(t0 + ty + i * 8) * HD_ + d0 + tx];
    __syncthreads();
#pragma unroll
    for (int i = 0; i < 4; i++)
      ob[(size_t)(d0 + ty + i * 8) * T_ + t0 + tx] = tile[tx][ty + i * 8];
    __syncthreads();
  }
}

// ---------------- 128x128 bf16 GEMM, B transposed ([N][K]) ----------------
template <int EPI>
__global__ __launch_bounds__(256) void gemm_bt(const bf16* __restrict__ A,
                                               const bf16* __restrict__ Bt,
                                               bf16* __restrict__ qb, bf16* __restrict__ kb,
                                               bf16* __restrict__ vb, float* __restrict__ fout,
                                               int M, int N, int K) {
  __shared__ __align__(16) bf16 lds_a[128 * 32];
  __shared__ __align__(16) bf16 lds_b[128 * 32];
  int n0 = blockIdx.x * 128, m0 = blockIdx.y * 128;
  int tid = threadIdx.x, wave = tid >> 6, lane = tid & 63;
  int l16 = lane & 15, lhi = lane >> 4;
  int wr = wave >> 1, wc = wave & 1;
  f32x4 acc[4][4];
#pragma unroll
  for (int mt = 0; mt < 4; mt++)
#pragma unroll
    for (int nt = 0; nt < 4; nt++) acc[mt][nt] = (f32x4){0.f, 0.f, 0.f, 0.f};

  int sr = wave * 16 + (lane >> 2);
  int scol = (lane & 3) * 8;
  const bf16* ga = A + (size_t)(m0 + sr) * K + scol;
  const bf16* gb = Bt + (size_t)(n0 + sr) * K + scol;
  bf16* la0 = &lds_a[wave * 512];
  bf16* la1 = &lds_a[2048 + wave * 512];
  bf16* lb0 = &lds_b[wave * 512];
  bf16* lb1 = &lds_b[2048 + wave * 512];

  for (int k0 = 0; k0 < K; k0 += 32) {
    gld_lds16(ga + k0, la0);
    gld_lds16(ga + (size_t)64 * K + k0, la1);
    gld_lds16(gb + k0, lb0);
    gld_lds16(gb + (size_t)64 * K + k0, lb1);
    __syncthreads();
    bf16x8 af[4], bfr[4];
#pragma unroll
    for (int mt = 0; mt < 4; mt++)
      af[mt] = *(const bf16x8*)&lds_a[(wr * 64 + mt * 16 + l16) * 32 + 8 * lhi];
#pragma unroll
    for (int nt = 0; nt < 4; nt++)
      bfr[nt] = *(const bf16x8*)&lds_b[(wc * 64 + nt * 16 + l16) * 32 + 8 * lhi];
#pragma unroll
    for (int mt = 0; mt < 4; mt++)
#pragma unroll
      for (int nt = 0; nt < 4; nt++) acc[mt][nt] = MFMA16(af[mt], bfr[nt], acc[mt][nt]);
    __syncthreads();
  }

#pragma unroll
  for (int mt = 0; mt < 4; mt++)
#pragma unroll
    for (int nt = 0; nt < 4; nt++)
#pragma unroll
      for (int rr = 0; rr < 4; rr++) {
        int row = m0 + wr * 64 + mt * 16 + 4 * lhi + rr;
        int col = n0 + wc * 64 + nt * 16 + l16;
        float v = acc[mt][nt][rr];
        if (EPI == 0) {
          int b = row >> 11, t = row & (T_ - 1);
          int sec = col >> 10, c2 = col & 1023;
          int h = c2 >> 6, d = c2 & 63;
          size_t idx = ((size_t)(b * H_ + h) * T_ + t) * HD_ + d;
          if (sec == 0)
            qb[idx] = (bf16)(v * 0.03125f);  // SCALE = D^-0.5 = 1/32 folded into Q
          else if (sec == 1)
            kb[idx] = (bf16)v;
          else
            vb[idx] = (bf16)v;
        } else {
          fout[(size_t)row * N + col] = v;
        }
      }
}

// ---------------- causal flash attention v3 ----------------
// K/V^T are L2-resident (256 KB/head) -> read fragments directly from global,
// no K/V LDS staging, NO barriers. Each wave fully independent: 32 q rows.
// Per-wave LDS scratch only for the P operand-layout transpose.
// XCD swizzle: XCD k owns heads [8k,8k+8); heavy diagonal blocks first.
__global__ __launch_bounds__(256) void attn_kernel(const bf16* __restrict__ qbuf,
                                                   const bf16* __restrict__ kbuf,
                                                   const bf16* __restrict__ vtbuf,
                                                   bf16* __restrict__ obuf) {
  __shared__ __align__(16) bf16 plds[4][32 * 64];

  int bid = blockIdx.x;
  int xcd = bid & 7;
  int s0 = bid >> 3;
  int bh = xcd * 8 + (s0 >> 4);
  int qi = 15 - (s0 & 15);  // heavy blocks first
  int wave = threadIdx.x >> 6, lane = threadIdx.x & 63;
  int l16 = lane & 15, lhi = lane >> 4;
  int qw = qi * 128 + wave * 32;

  const bf16* Q = qbuf + (size_t)bh * T_ * HD_;
  const bf16* Kg = kbuf + (size_t)bh * T_ * HD_;
  const bf16* Vt = vtbuf + (size_t)bh * HD_ * T_;

  bf16x8 qf[2][2];
#pragma unroll
  for (int i = 0; i < 2; i++)
#pragma unroll
    for (int kk = 0; kk < 2; kk++)
      qf[i][kk] = *(const bf16x8*)(Q + (size_t)(qw + i * 16 + l16) * HD_ + kk * 32 + 8 * lhi);

  f32x4 acc[2][4];
#pragma unroll
  for (int i = 0; i < 2; i++)
#pragma unroll
    for (int dt = 0; dt < 4; dt++) acc[i][dt] = (f32x4){0.f, 0.f, 0.f, 0.f};
  float m_r[2][4], l_r[2][4];
#pragma unroll
  for (int i = 0; i < 2; i++)
#pragma unroll
    for (int rr = 0; rr < 4; rr++) {
      m_r[i][rr] = -1e30f;
      l_r[i][rr] = 0.f;
    }

  bf16* pb = plds[wave];
  int nt = qw / 64 + 1;  // tiles of 64 kv; last is partially masked

  for (int t = 0; t < nt; ++t) {
    int jb = t * 64;
    // ---- K fragments straight from global (L2-hit) + QK^T ----
    bf16x8 kf0[4], kf1[4];
#pragma unroll
    for (int jt = 0; jt < 4; jt++) {
      const bf16* kp = Kg + (size_t)(jb + jt * 16 + l16) * HD_ + 8 * lhi;
      kf0[jt] = *(const bf16x8*)kp;
      kf1[jt] = *(const bf16x8*)(kp + 32);
    }
    f32x4 s[2][4];
#pragma unroll
    for (int jt = 0; jt < 4; jt++)
#pragma unroll
      for (int i = 0; i < 2; i++) {
        f32x4 z = (f32x4){0.f, 0.f, 0.f, 0.f};
        z = MFMA16(qf[i][0], kf0[jt], z);
        s[i][jt] = MFMA16(qf[i][1], kf1[jt], z);
      }
    // ---- V fragments: issue NOW (independent of softmax -> latency hidden) ----
    bf16x8 vf0[4], vf1[4];
#pragma unroll
    for (int dt = 0; dt < 4; dt++) {
      const bf16* vp = Vt + (size_t)(dt * 16 + l16) * T_ + jb + 8 * lhi;
      vf0[dt] = *(const bf16x8*)vp;
      vf1[dt] = *(const bf16x8*)(vp + 32);
    }
    // ---- causal mask (last tile only) ----
    if (jb + 63 > qw) {
#pragma unroll
      for (int i = 0; i < 2; i++)
#pragma unroll
        for (int jt = 0; jt < 4; jt++)
#pragma unroll
          for (int rr = 0; rr < 4; rr++)
            if (jb + jt * 16 + l16 > qw + i * 16 + 4 * lhi + rr) s[i][jt][rr] = -1e30f;
    }
    // ---- online softmax (rows spread over 16-lane groups) ----
    float mx[2][4];
#pragma unroll
    for (int i = 0; i < 2; i++)
#pragma unroll
      for (int rr = 0; rr < 4; rr++)
        mx[i][rr] = fmaxf(fmaxf(s[i][0][rr], s[i][1][rr]), fmaxf(s[i][2][rr], s[i][3][rr]));
#pragma unroll
    for (int off = 1; off < 16; off <<= 1)
#pragma unroll
      for (int i = 0; i < 2; i++)
#pragma unroll
        for (int rr = 0; rr < 4; rr++) mx[i][rr] = fmaxf(mx[i][rr], __shfl_xor(mx[i][rr], off));
    float sum[2][4], sc[2][4];
#pragma unroll
    for (int i = 0; i < 2; i++)
#pragma unroll
      for (int rr = 0; rr < 4; rr++) {
        float mn = fmaxf(m_r[i][rr], mx[i][rr]);
        sc[i][rr] = __expf(m_r[i][rr] - mn);
        m_r[i][rr] = mn;
        float su = 0.f;
#pragma unroll
        for (int jt = 0; jt < 4; jt++) {
          s[i][jt][rr] = __expf(s[i][jt][rr] - mn);
          su += s[i][jt][rr];
        }
        sum[i][rr] = su;
      }
#pragma unroll
    for (int off = 1; off < 16; off <<= 1)
#pragma unroll
      for (int i = 0; i < 2; i++)
#pragma unroll
        for (int rr = 0; rr < 4; rr++) sum[i][rr] += __shfl_xor(sum[i][rr], off);
#pragma unroll
    for (int i = 0; i < 2; i++)
#pragma unroll
      for (int rr = 0; rr < 4; rr++) l_r[i][rr] = l_r[i][rr] * sc[i][rr] + sum[i][rr];
#pragma unroll
    for (int i = 0; i < 2; i++)
#pragma unroll
      for (int dt = 0; dt < 4; dt++)
#pragma unroll
        for (int rr = 0; rr < 4; rr++) acc[i][dt][rr] *= sc[i][rr];

    // ---- P -> bf16 A-fragments via per-wave swizzled LDS (no barrier) ----
#pragma unroll
    for (int i = 0; i < 2; i++)
#pragma unroll
      for (int jt = 0; jt < 4; jt++)
#pragma unroll
        for (int rr = 0; rr < 4; rr++) {
          int prow = i * 16 + 4 * lhi + rr;
          int byte = prow * 128 + ((jt * 32 + 2 * l16) ^ ((prow & 7) << 4));
          *(bf16*)((char*)pb + byte) = (bf16)s[i][jt][rr];
        }
    bf16x8 pf[2][2];
#pragma unroll
    for (int i = 0; i < 2; i++)
#pragma unroll
      for (int kk = 0; kk < 2; kk++) {
        int prow = i * 16 + l16;
        int byte = prow * 128 + (((kk * 64) + lhi * 16) ^ ((prow & 7) << 4));
        pf[i][kk] = *(const bf16x8*)((const char*)pb + byte);
      }
    // ---- PV ----
#pragma unroll
    for (int dt = 0; dt < 4; dt++)
#pragma unroll
      for (int i = 0; i < 2; i++) {
        acc[i][dt] = MFMA16(pf[i][0], vf0[dt], acc[i][dt]);
        acc[i][dt] = MFMA16(pf[i][1], vf1[dt], acc[i][dt]);
      }
  }

  int b = bh >> 4, h = bh & 15;
#pragma unroll
  for (int i = 0; i < 2; i++)
#pragma unroll
    for (int dt = 0; dt < 4; dt++)
#pragma unroll
      for (int rr = 0; rr < 4; rr++) {
        int row = qw + i * 16 + 4 * lhi + rr;
        obuf[((size_t)(b * T_ + row)) * D_ + h * 64 + dt * 16 + l16] =
            (bf16)(acc[i][dt][rr] / l_r[i][rr]);
      }
}

extern "C" void kernel_launch(void* const* d_in, const int* in_sizes, int n_in, void* d_out,
                              int out_size, void* d_ws, size_t ws_size, hipStream_t stream) {
  const float* x = (const float*)d_in[0];
  const float* wqkv = (const float*)d_in[1];
  const float* wo = (const float*)d_in[2];
  float* out = (float*)d_out;
  char* ws = (char*)d_ws;

  bf16* xb = (bf16*)ws;                     // 16 MB  [8192][1024]
  bf16* wqkvt = (bf16*)(ws + (16u << 20));  // 6 MB   [3072][1024]
  bf16* wot = (bf16*)(ws + (22u << 20));    // 2 MB   [1024][1024]
  bf16* qb = (bf16*)(ws + (24u << 20));     // 16 MB  [B,H,T,64]
  bf16* kb = (bf16*)(ws + (40u << 20));     // 16 MB  [B,H,T,64]
  bf16* vb = (bf16*)(ws + (56u << 20));     // 16 MB  [B,H,T,64]
  bf16* vtb = (bf16*)(ws + (72u << 20));    // 16 MB  [B,H,64,T]
  bf16* ao = (bf16*)(ws + (88u << 20));     // 16 MB  [8192][1024]

  cvt_f32_bf16<<<8192, 256, 0, stream>>>(x, xb);
  transpose_f32_bf16<<<dim3(96, 32), dim3(32, 8), 0, stream>>>(wqkv, wqkvt, 1024, 3072);
  transpose_f32_bf16<<<dim3(32, 32), dim3(32, 8), 0, stream>>>(wo, wot, 1024, 1024);
  gemm_bt<0><<<dim3(24, 64), 256, 0, stream>>>(xb, wqkvt, qb, kb, vb, nullptr,
                                               B_ * T_, 3 * D_, D_);
  transpose_v<<<dim3(64, 64), dim3(32, 8), 0, stream>>>(vb, vtb);
  attn_kernel<<<1024, 256, 0, stream>>>(qb, kb, vtb, ao);
  gemm_bt<1><<<dim3(8, 64), 256, 0, stream>>>(ao, wot, nullptr, nullptr, nullptr, out,
                                              B_ * T_, D_, D_);
}

// Round 4
// 252.212 us; speedup vs baseline: 1.3950x; 1.3950x over previous
//
#include <hip/hip_runtime.h>
#include <hip/hip_bf16.h>

#define B_ 4
#define T_ 2048
#define D_ 1024
#define H_ 16
#define HD_ 64

typedef __bf16 bf16;
typedef __bf16 bf16x8 __attribute__((ext_vector_type(8)));
typedef __bf16 bf16x4 __attribute__((ext_vector_type(4)));
typedef float f32x4 __attribute__((ext_vector_type(4)));
typedef float f32x16 __attribute__((ext_vector_type(16)));

#define MFMA16(a, b, c) __builtin_amdgcn_mfma_f32_16x16x32_bf16(a, b, c, 0, 0, 0)
#define MFMA32(a, b, c) __builtin_amdgcn_mfma_f32_32x32x16_bf16(a, b, c, 0, 0, 0)

__device__ inline void gld_lds16(const bf16* g, bf16* l) {
  __builtin_amdgcn_global_load_lds((const __attribute__((address_space(1))) void*)g,
                                   (__attribute__((address_space(3))) void*)l, 16, 0, 0);
}

__device__ inline unsigned pkbf16(float a, float b) {
  unsigned r;
  asm("v_cvt_pk_bf16_f32 %0, %1, %2" : "=v"(r) : "v"(a), "v"(b));
  return r;
}
__device__ inline void pl32swap(unsigned& x, unsigned& y) {
  asm("v_permlane32_swap_b32 %0, %1" : "+v"(x), "+v"(y));
}

// pack 8 consecutive-kv P values (this lane + partner lane) into one B-frag
#define PACKJ(dst, S, base)                        \
  {                                                \
    unsigned w0 = pkbf16(S[base + 0], S[base + 1]); \
    unsigned w2 = pkbf16(S[base + 4], S[base + 5]); \
    pl32swap(w0, w2);                              \
    unsigned w1 = pkbf16(S[base + 2], S[base + 3]); \
    unsigned w3 = pkbf16(S[base + 6], S[base + 7]); \
    pl32swap(w1, w3);                              \
    int4 wi = {(int)w0, (int)w1, (int)w2, (int)w3}; \
    dst = __builtin_bit_cast(bf16x8, wi);          \
  }

// ---------------- convert x f32 -> bf16 ----------------
__global__ void cvt_f32_bf16(const float* __restrict__ in, bf16* __restrict__ out) {
  int i = (blockIdx.x * 256 + threadIdx.x) * 4;
  float4 v = *(const float4*)(in + i);
  bf16x4 o = {(bf16)v.x, (bf16)v.y, (bf16)v.z, (bf16)v.w};
  *(bf16x4*)(out + i) = o;
}

// ---------------- transpose f32 [R][C] -> bf16 [C][R] ----------------
__global__ void transpose_f32_bf16(const float* __restrict__ in, bf16* __restrict__ out,
                                   int R, int C) {
  __shared__ float tile[32][33];
  int c0 = blockIdx.x * 32, r0 = blockIdx.y * 32;
  int tx = threadIdx.x, ty = threadIdx.y;
#pragma unroll
  for (int i = 0; i < 4; i++)
    tile[ty + i * 8][tx] = in[(size_t)(r0 + ty + i * 8) * C + c0 + tx];
  __syncthreads();
#pragma unroll
  for (int i = 0; i < 4; i++)
    out[(size_t)(c0 + ty + i * 8) * R + r0 + tx] = (bf16)tile[tx][ty + i * 8];
}

// ---------------- transpose V bf16 [bh][T][64] -> [bh][64][T] ----------------
__global__ void transpose_v(const bf16* __restrict__ in, bf16* __restrict__ out) {
  __shared__ bf16 tile[32][33];
  int bh = blockIdx.y;
  int t0 = blockIdx.x * 32;
  int tx = threadIdx.x, ty = threadIdx.y;
  const bf16* ib = in + (size_t)bh * T_ * HD_;
  bf16* ob = out + (size_t)bh * HD_ * T_;
#pragma unroll
  for (int d0 = 0; d0 < 64; d0 += 32) {
#pragma unroll
    for (int i = 0; i < 4; i++)
      tile[ty + i * 8][tx] = ib[(size_t)(t0 + ty + i * 8) * HD_ + d0 + tx];
    __syncthreads();
#pragma unroll
    for (int i = 0; i < 4; i++)
      ob[(size_t)(d0 + ty + i * 8) * T_ + t0 + tx] = tile[tx][ty + i * 8];
    __syncthreads();
  }
}

// ---------------- 128x128 bf16 GEMM, B transposed ([N][K]) ----------------
template <int EPI>
__global__ __launch_bounds__(256) void gemm_bt(const bf16* __restrict__ A,
                                               const bf16* __restrict__ Bt,
                                               bf16* __restrict__ qb, bf16* __restrict__ kb,
                                               bf16* __restrict__ vb, float* __restrict__ fout,
                                               int M, int N, int K) {
  __shared__ __align__(16) bf16 lds_a[128 * 32];
  __shared__ __align__(16) bf16 lds_b[128 * 32];
  int n0 = blockIdx.x * 128, m0 = blockIdx.y * 128;
  int tid = threadIdx.x, wave = tid >> 6, lane = tid & 63;
  int l16 = lane & 15, lhi = lane >> 4;
  int wr = wave >> 1, wc = wave & 1;
  f32x4 acc[4][4];
#pragma unroll
  for (int mt = 0; mt < 4; mt++)
#pragma unroll
    for (int nt = 0; nt < 4; nt++) acc[mt][nt] = (f32x4){0.f, 0.f, 0.f, 0.f};

  int sr = wave * 16 + (lane >> 2);
  int scol = (lane & 3) * 8;
  const bf16* ga = A + (size_t)(m0 + sr) * K + scol;
  const bf16* gb = Bt + (size_t)(n0 + sr) * K + scol;
  bf16* la0 = &lds_a[wave * 512];
  bf16* la1 = &lds_a[2048 + wave * 512];
  bf16* lb0 = &lds_b[wave * 512];
  bf16* lb1 = &lds_b[2048 + wave * 512];

  for (int k0 = 0; k0 < K; k0 += 32) {
    gld_lds16(ga + k0, la0);
    gld_lds16(ga + (size_t)64 * K + k0, la1);
    gld_lds16(gb + k0, lb0);
    gld_lds16(gb + (size_t)64 * K + k0, lb1);
    __syncthreads();
    bf16x8 af[4], bfr[4];
#pragma unroll
    for (int mt = 0; mt < 4; mt++)
      af[mt] = *(const bf16x8*)&lds_a[(wr * 64 + mt * 16 + l16) * 32 + 8 * lhi];
#pragma unroll
    for (int nt = 0; nt < 4; nt++)
      bfr[nt] = *(const bf16x8*)&lds_b[(wc * 64 + nt * 16 + l16) * 32 + 8 * lhi];
#pragma unroll
    for (int mt = 0; mt < 4; mt++)
#pragma unroll
      for (int nt = 0; nt < 4; nt++) acc[mt][nt] = MFMA16(af[mt], bfr[nt], acc[mt][nt]);
    __syncthreads();
  }

#pragma unroll
  for (int mt = 0; mt < 4; mt++)
#pragma unroll
    for (int nt = 0; nt < 4; nt++)
#pragma unroll
      for (int rr = 0; rr < 4; rr++) {
        int row = m0 + wr * 64 + mt * 16 + 4 * lhi + rr;
        int col = n0 + wc * 64 + nt * 16 + l16;
        float v = acc[mt][nt][rr];
        if (EPI == 0) {
          int b = row >> 11, t = row & (T_ - 1);
          int sec = col >> 10, c2 = col & 1023;
          int h = c2 >> 6, d = c2 & 63;
          size_t idx = ((size_t)(b * H_ + h) * T_ + t) * HD_ + d;
          if (sec == 0)
            qb[idx] = (bf16)(v * 0.03125f);  // SCALE = D^-0.5 = 1/32 folded into Q
          else if (sec == 1)
            kb[idx] = (bf16)v;
          else
            vb[idx] = (bf16)v;
        } else {
          fout[(size_t)row * N + col] = v;
        }
      }
}

// ---------------- causal flash attention v4 ----------------
// 1-wave blocks (64 thr), 32 q rows each. Swapped QK^T (A=K,B=Q) with
// 32x32x16 MFMA: lane's q = lane&31 uniform -> softmax reduce = in-lane +
// one shfl_xor(32). P->PV B-frags packed in-register (cvt_pk_bf16 +
// permlane32_swap). PV swapped too (A=V^T). K prefetched one tile ahead.
// K/V^T read from global (L2-resident per head). Heavy q-tiles first,
// heads pinned to XCDs via bid&7.
__global__ __launch_bounds__(64) void attn_kernel(const bf16* __restrict__ qbuf,
                                                  const bf16* __restrict__ kbuf,
                                                  const bf16* __restrict__ vtbuf,
                                                  bf16* __restrict__ obuf) {
  __shared__ float tlds[64 * 33];
  int bid = blockIdx.x;
  int bh = (bid & 7) * 8 + ((bid >> 3) & 7);
  int qw = (63 - (bid >> 6)) * 32;  // heavy chunks dispatched first
  int lane = threadIdx.x;
  int q = lane & 31, hi = lane >> 5;

  const bf16* Q = qbuf + (size_t)bh * T_ * HD_;
  const bf16* Kg = kbuf + (size_t)bh * T_ * HD_;
  const bf16* Vt = vtbuf + (size_t)bh * HD_ * T_;

  bf16x8 qf[4];
#pragma unroll
  for (int j = 0; j < 4; j++)
    qf[j] = *(const bf16x8*)(Q + (size_t)(qw + q) * HD_ + j * 16 + hi * 8);

  const bf16* kbase = Kg + (size_t)q * HD_ + hi * 8;
  const bf16* vbase = Vt + (size_t)q * T_ + hi * 8;

  f32x16 o1, o2;
#pragma unroll
  for (int r = 0; r < 16; r++) {
    o1[r] = 0.f;
    o2[r] = 0.f;
  }
  float m_r = -1e30f, l_r = 0.f;
  int nt = qw / 64 + 1;

  bf16x8 kA[8], kB[8];
#pragma unroll
  for (int j = 0; j < 4; j++) {
    kA[j] = *(const bf16x8*)(kbase + j * 16);
    kA[4 + j] = *(const bf16x8*)(kbase + 32 * HD_ + j * 16);
  }

  auto body = [&](bf16x8(&kc)[8], bf16x8(&kp)[8], int t) {
    int jb = t * 64;
    // ---- QK^T: S^T[kv][q] ----
    f32x16 s1, s2;
#pragma unroll
    for (int r = 0; r < 16; r++) {
      s1[r] = 0.f;
      s2[r] = 0.f;
    }
    __builtin_amdgcn_s_setprio(1);
#pragma unroll
    for (int j = 0; j < 4; j++) s1 = MFMA32(kc[j], qf[j], s1);
#pragma unroll
    for (int j = 0; j < 4; j++) s2 = MFMA32(kc[4 + j], qf[j], s2);
    __builtin_amdgcn_s_setprio(0);
    // ---- prefetch next K tile (hidden under softmax+PV) ----
    if (t + 1 < nt) {
      int jn = (jb + 64) * HD_;
#pragma unroll
      for (int j = 0; j < 4; j++) {
        kp[j] = *(const bf16x8*)(kbase + jn + j * 16);
        kp[4 + j] = *(const bf16x8*)(kbase + jn + 32 * HD_ + j * 16);
      }
    }
    // ---- V frags for current tile (independent of softmax) ----
    bf16x8 vf[8];
#pragma unroll
    for (int j = 0; j < 4; j++) {
      vf[j] = *(const bf16x8*)(vbase + jb + j * 16);
      vf[4 + j] = *(const bf16x8*)(vbase + 32 * T_ + jb + j * 16);
    }
    // ---- causal mask (last tile only) ----
    if (t == nt - 1) {
#pragma unroll
      for (int r = 0; r < 16; r++) {
        int kv = (r & 3) + 8 * (r >> 2) + 4 * hi;
        if (jb + kv > qw + q) s1[r] = -1e30f;
        if (jb + kv + 32 > qw + q) s2[r] = -1e30f;
      }
    }
    // ---- online softmax: in-lane + one shfl ----
    float mx = s1[0];
#pragma unroll
    for (int r = 1; r < 16; r++) mx = fmaxf(mx, s1[r]);
#pragma unroll
    for (int r = 0; r < 16; r++) mx = fmaxf(mx, s2[r]);
    mx = fmaxf(mx, __shfl_xor(mx, 32));
    float mn = fmaxf(m_r, mx);
    float sc = __expf(m_r - mn);
    m_r = mn;
    float su = 0.f;
#pragma unroll
    for (int r = 0; r < 16; r++) {
      s1[r] = __expf(s1[r] - mn);
      su += s1[r];
    }
#pragma unroll
    for (int r = 0; r < 16; r++) {
      s2[r] = __expf(s2[r] - mn);
      su += s2[r];
    }
    su += __shfl_xor(su, 32);
    l_r = l_r * sc + su;
#pragma unroll
    for (int r = 0; r < 16; r++) {
      o1[r] *= sc;
      o2[r] *= sc;
    }
    // ---- pack P into PV B-frags (in-register) ----
    bf16x8 pf0, pf1, pf2, pf3;
    PACKJ(pf0, s1, 0);
    PACKJ(pf1, s1, 8);
    PACKJ(pf2, s2, 0);
    PACKJ(pf3, s2, 8);
    // ---- PV: O^T[d][q] ----
    __builtin_amdgcn_s_setprio(1);
    o1 = MFMA32(vf[0], pf0, o1);
    o2 = MFMA32(vf[4], pf0, o2);
    o1 = MFMA32(vf[1], pf1, o1);
    o2 = MFMA32(vf[5], pf1, o2);
    o1 = MFMA32(vf[2], pf2, o1);
    o2 = MFMA32(vf[6], pf2, o2);
    o1 = MFMA32(vf[3], pf3, o1);
    o2 = MFMA32(vf[7], pf3, o2);
    __builtin_amdgcn_s_setprio(0);
  };

  int t = 0;
  while (true) {
    body(kA, kB, t);
    if (++t == nt) break;
    body(kB, kA, t);
    if (++t == nt) break;
  }

  // ---- epilogue: O^T -> LDS transpose -> coalesced bf16 stores ----
  float inv = 1.f / l_r;
#pragma unroll
  for (int r = 0; r < 16; r++) {
    int d = (r & 3) + 8 * (r >> 2) + 4 * hi;
    tlds[d * 33 + q] = o1[r] * inv;
    tlds[(32 + d) * 33 + q] = o2[r] * inv;
  }
  __syncthreads();
  int b = bh >> 4, h = bh & 15;
#pragma unroll
  for (int pass = 0; pass < 4; pass++) {
    int row = qw + pass * 8 + (lane >> 3);
    int dcol = (lane & 7) * 8;
    bf16x8 ov;
#pragma unroll
    for (int e = 0; e < 8; e++) ov[e] = (bf16)tlds[(dcol + e) * 33 + pass * 8 + (lane >> 3)];
    *(bf16x8*)(obuf + ((size_t)(b * T_ + row)) * D_ + h * 64 + dcol) = ov;
  }
}

extern "C" void kernel_launch(void* const* d_in, const int* in_sizes, int n_in, void* d_out,
                              int out_size, void* d_ws, size_t ws_size, hipStream_t stream) {
  const float* x = (const float*)d_in[0];
  const float* wqkv = (const float*)d_in[1];
  const float* wo = (const float*)d_in[2];
  float* out = (float*)d_out;
  char* ws = (char*)d_ws;

  bf16* xb = (bf16*)ws;                     // 16 MB  [8192][1024]
  bf16* wqkvt = (bf16*)(ws + (16u << 20));  // 6 MB   [3072][1024]
  bf16* wot = (bf16*)(ws + (22u << 20));    // 2 MB   [1024][1024]
  bf16* qb = (bf16*)(ws + (24u << 20));     // 16 MB  [B,H,T,64]
  bf16* kb = (bf16*)(ws + (40u << 20));     // 16 MB  [B,H,T,64]
  bf16* vb = (bf16*)(ws + (56u << 20));     // 16 MB  [B,H,T,64]
  bf16* vtb = (bf16*)(ws + (72u << 20));    // 16 MB  [B,H,64,T]
  bf16* ao = (bf16*)(ws + (88u << 20));     // 16 MB  [8192][1024]

  cvt_f32_bf16<<<8192, 256, 0, stream>>>(x, xb);
  transpose_f32_bf16<<<dim3(96, 32), dim3(32, 8), 0, stream>>>(wqkv, wqkvt, 1024, 3072);
  transpose_f32_bf16<<<dim3(32, 32), dim3(32, 8), 0, stream>>>(wo, wot, 1024, 1024);
  gemm_bt<0><<<dim3(24, 64), 256, 0, stream>>>(xb, wqkvt, qb, kb, vb, nullptr,
                                               B_ * T_, 3 * D_, D_);
  transpose_v<<<dim3(64, 64), dim3(32, 8), 0, stream>>>(vb, vtb);
  attn_kernel<<<4096, 64, 0, stream>>>(qb, kb, vtb, ao);
  gemm_bt<1><<<dim3(8, 64), 256, 0, stream>>>(ao, wot, nullptr, nullptr, nullptr, out,
                                              B_ * T_, D_, D_);
}